// Round 5
// baseline (185.179 us; speedup 1.0000x reference)
//
#include <hip/hip_runtime.h>
#include <math.h>

// Closed-form replacement for the reference:
//   - spectrum has exactly 2 nonzero bins per (b,c) plane: (h0,w0) and (511-h0,511-w0),
//     both with value 1 + i*phase
//   - ifft2 real part: v[y,x] = cos(t1) - p*sin(t1) + cos(t2) - p*sin(t2), scaled 1/(H*W)
//     t1 = 2*pi*((h0*y + w0*x) mod 512)/512 ; t2 with (511-h0, 511-w0)
//   - Parseval: plane norm sum(w^2) = S/(H*W), S = s1+s2,
//     s_i = (1+p^2)/2 unless self-conjugate bin (then 1)
//   - out = clip(x + 16*strength/(512*sqrt(S)) * v, 0, 1)
//
// R1 -> R3: ROWS 32->8 (6144 blocks), hoisted 4-deep load MLP, NT stores.
//           74.9us -> ~59us.
// R3 -> R4: hw v_sin/v_cos (revolutions, exact on the 2pi/512 grid), no LDS.
//           NEUTRAL (~59us) -> not VALU-bound. Occ 60%, 2.56 TB/s.
// R4 -> R5: persistent grid = 2048 blocks (8/CU exactly), 3 tiles/block
//           stride loop: flat residency, no generation ramp/drain. Loads
//           issue first each iteration; params+trig overlap load latency.
//           Row coeffs computed in-loop (scalar regs) to stay <=64 VGPR
//           so __launch_bounds__(256,8) holds 8 waves/SIMD.

namespace {

constexpr int H = 512, W = 512, B = 32, C = 3;
constexpr int ROWS = 8;            // rows per tile
constexpr int TPB = 256;           // 128 float4-lanes x 2 row-phases
constexpr int NBLK = 2048;         // 8 blocks/CU x 256 CU — persistent
constexpr int NTILES = (B * C) * (H / ROWS);   // 96 planes x 64 tiles = 6144
constexpr int TILES_PER_BLK = NTILES / NBLK;   // 3

typedef float floatx4 __attribute__((ext_vector_type(4)));

__global__ __launch_bounds__(TPB, 8) void fourier_noise_kernel(
    const float* __restrict__ xin,
    const float* __restrict__ phases,
    const float* __restrict__ strengths,
    const int* __restrict__ idx_h,
    const int* __restrict__ idx_w,
    float* __restrict__ out)
{
    const int xg   = (threadIdx.x & 127) << 2;  // column group 0..508
    const int rsub = threadIdx.x >> 7;          // 0 or 1 (wave-uniform)
    constexpr float INV = 1.0f / 512.0f;        // grid index -> revolutions

    const int t0 = blockIdx.x * TILES_PER_BLK;

#pragma unroll 1
    for (int t = t0; t < t0 + TILES_PER_BLK; ++t) {
        const int pl   = t >> 6;          // plane 0..95
        const int row0 = (t & 63) << 3;   // row tile base

        // ---- issue the 4 vector loads FIRST (address needs only t) ----
        const uint32_t off0 = (uint32_t)pl * (uint32_t)(H * W)
                            + (uint32_t)(row0 + rsub) * (uint32_t)W + (uint32_t)xg;
        const floatx4 vi0 = *reinterpret_cast<const floatx4*>(xin + off0);
        const floatx4 vi1 = *reinterpret_cast<const floatx4*>(xin + off0 + 2u * W);
        const floatx4 vi2 = *reinterpret_cast<const floatx4*>(xin + off0 + 4u * W);
        const floatx4 vi3 = *reinterpret_cast<const floatx4*>(xin + off0 + 6u * W);

        // ---- scalar params (wave-uniform; overlap with loads in flight) ----
        const int b = pl / C;
        const int c = pl % C;
        int d = (c - b) % 3; if (d < 0) d += 3;     // CRT inverse pairing
        const int i = b + B * ((2 * d) % 3);

        const int   h0 = idx_h[i];
        const int   w0 = idx_w[i];
        const float p  = phases[i];
        const float st = strengths[pl];

        const float halfE = 0.5f * (1.0f + p * p);
        const float s1 = (((h0 & 255) == 0) && ((w0 & 255) == 0)) ? 1.0f : halfE;
        const float s2 = ((h0 == 255 || h0 == 511) && (w0 == 255 || w0 == 511)) ? 1.0f : halfE;
        const float g  = (16.0f / 512.0f) * st * rsqrtf(s1 + s2);

        const int h0r = 511 - h0;
        const int w0r = 511 - w0;

        // ---- per-thread column trig (held across the row loop) ----
        float cx1[4], sx1[4], cx2[4], sx2[4];
#pragma unroll
        for (int j = 0; j < 4; ++j) {
            const int xx = xg + j;
            const float a1 = (float)((w0  * xx) & 511) * INV;
            const float a2 = (float)((w0r * xx) & 511) * INV;
            sx1[j] = __builtin_amdgcn_sinf(a1);
            cx1[j] = __builtin_amdgcn_cosf(a1);
            sx2[j] = __builtin_amdgcn_sinf(a2);
            cx2[j] = __builtin_amdgcn_cosf(a2);
        }

        // ---- row loop: coeffs in scalar regs (reused), consume loads oldest-first
#define DO_ROW(vi, it)                                                          \
        {                                                                       \
            const int y = row0 + rsub + 2 * (it);                               \
            const float a1 = (float)((h0  * y) & 511) * INV;                    \
            const float a2 = (float)((h0r * y) & 511) * INV;                    \
            const float sy1 = __builtin_amdgcn_sinf(a1);                        \
            const float cy1 = __builtin_amdgcn_cosf(a1);                        \
            const float sy2 = __builtin_amdgcn_sinf(a2);                        \
            const float cy2 = __builtin_amdgcn_cosf(a2);                        \
            const float A1 = fmaf(-p, sy1, cy1), B1 = -fmaf(p, cy1, sy1);       \
            const float A2 = fmaf(-p, sy2, cy2), B2 = -fmaf(p, cy2, sy2);       \
            floatx4 vo;                                                         \
            _Pragma("unroll")                                                   \
            for (int j = 0; j < 4; ++j) {                                       \
                float v = cx1[j] * A1 + sx1[j] * B1 + cx2[j] * A2 + sx2[j] * B2;\
                vo[j] = fminf(fmaxf(fmaf(g, v, vi[j]), 0.0f), 1.0f);            \
            }                                                                   \
            __builtin_nontemporal_store(vo,                                     \
                reinterpret_cast<floatx4*>(out + off0 + 2u * (it) * W));        \
        }

        DO_ROW(vi0, 0)
        DO_ROW(vi1, 1)
        DO_ROW(vi2, 2)
        DO_ROW(vi3, 3)
#undef DO_ROW
    }
}

} // namespace

extern "C" void kernel_launch(void* const* d_in, const int* in_sizes, int n_in,
                              void* d_out, int out_size, void* d_ws, size_t ws_size,
                              hipStream_t stream) {
    const float* x         = (const float*)d_in[0];
    const float* phases    = (const float*)d_in[1];
    const float* strengths = (const float*)d_in[2];
    const int*   idx_h     = (const int*)d_in[3];
    const int*   idx_w     = (const int*)d_in[4];
    float*       out       = (float*)d_out;

    fourier_noise_kernel<<<dim3(NBLK), dim3(TPB), 0, stream>>>(
        x, phases, strengths, idx_h, idx_w, out);
}